// Round 3
// baseline (30543.655 us; speedup 1.0000x reference)
//
#include <hip/hip_runtime.h>
#include <math.h>

#define NEG10K -10000.0f
// K=12 tags, START=10, STOP=11, B=64, T=1024, V=50000, D=256, Hh=256, 4Hh=1024

// ---------------- workspace layout (float offsets), total ~12.6 MB ----------------
static const size_t OFF_WT_IH = 0;                  // [2][256][1024]  Wih^T per dir
static const size_t OFF_WT_HH = 524288;             // [2][256][1024]  Whh^T per dir
static const size_t OFF_BIAS  = 1048576;            // [2][1024]       bih+bhh
static const size_t OFF_WTAGD = 1050624;            // [2][16][256]    Wtag halves, k-padded to 16
static const size_t OFF_BTAG  = 1058816;            // [16]
static const size_t OFF_FEATS = 1058832;            // [2][64][1024][16] per-dir partial feats
static const size_t WS_FLOATS = OFF_FEATS + 2097152;

__device__ __forceinline__ float sigf(float x) { return 1.0f / (1.0f + expf(-x)); }

// ---------------- weight transposes: [1024][256] -> [256][1024] ----------------
__global__ __launch_bounds__(256) void k_transpose(
    const float* __restrict__ wih_f, const float* __restrict__ wih_b,
    const float* __restrict__ whh_f, const float* __restrict__ whh_b,
    float* __restrict__ ws) {
  __shared__ float tile[32][33];
  int z = blockIdx.z;
  const float* src = (z == 0) ? wih_f : (z == 1) ? wih_b : (z == 2) ? whh_f : whh_b;
  float* dst = ws + ((z < 2) ? (OFF_WT_IH + (size_t)z * 262144)
                             : (OFF_WT_HH + (size_t)(z - 2) * 262144));
  int r0 = blockIdx.y * 32;  // over 1024 rows of src
  int c0 = blockIdx.x * 32;  // over 256 cols of src
  int tid = threadIdx.x;
  int c = tid & 31, rg = tid >> 5;
#pragma unroll
  for (int i = 0; i < 4; ++i) {
    int r = rg * 4 + i;
    tile[r][c] = src[(size_t)(r0 + r) * 256 + c0 + c];
  }
  __syncthreads();
  int r2 = tid & 31, cg = tid >> 5;
#pragma unroll
  for (int i = 0; i < 4; ++i) {
    int ccv = cg * 4 + i;
    dst[(size_t)(c0 + ccv) * 1024 + r0 + r2] = tile[r2][ccv];
  }
}

// ---------------- small prep: bias combine, Wtag halves (pad K->16), btag pad ----------------
__global__ __launch_bounds__(256) void k_prep_small(
    const float* __restrict__ bih_f, const float* __restrict__ bhh_f,
    const float* __restrict__ bih_b, const float* __restrict__ bhh_b,
    const float* __restrict__ wtag, const float* __restrict__ btag,
    float* __restrict__ ws) {
  int i = blockIdx.x * 256 + threadIdx.x;
  if (i < 2048) {
    int d = i >> 10, n = i & 1023;
    ws[OFF_BIAS + i] = d ? (bih_b[n] + bhh_b[n]) : (bih_f[n] + bhh_f[n]);
  } else if (i < 2048 + 8192) {
    int r = i - 2048;
    int d = r >> 12, rem = r & 4095;
    int k = rem >> 8, j = rem & 255;  // Wtag half d: rows k<12 real, 12..15 zero
    ws[OFF_WTAGD + r] = (k < 12) ? wtag[(size_t)k * 512 + d * 256 + j] : 0.0f;
  } else if (i < 2048 + 8192 + 16) {
    int kk = i - 10240;
    ws[OFF_BTAG + kk] = (kk < 12) ? btag[kk] : 0.0f;
  }
}

// ---------------- fused LSTM + tag-head ----------------
// 64 WGs = (32 batch-pairs) x (2 dirs); 512 threads (8 waves, 2/SIMD).
// Thread t owns gate columns {2t, 2t+1} via float2 coalesced weight loads.
__global__ __launch_bounds__(512) void k_lstm(
    const float* __restrict__ ws_c, const int* __restrict__ sentence,
    const float* __restrict__ emb, const float* __restrict__ h0p,
    const float* __restrict__ c0p, const int* __restrict__ seq_lens,
    float* __restrict__ ws_mut) {
  int d = blockIdx.x & 1;          // round-robin XCD dispatch -> one dir per XCD parity
  int pr = blockIdx.x >> 1;
  int b0 = pr * 2, b1 = b0 + 1;
  const float* Wih = ws_c + OFF_WT_IH + (size_t)d * 262144;  // [256][1024]
  const float* Whh = ws_c + OFF_WT_HH + (size_t)d * 262144;  // [256][1024]

  __shared__ float h_s[2][256];
  __shared__ float x_s[2][2][256];        // [buf][batch][256]
  __shared__ float z_s[2][1024];
  __shared__ int   sent_s[2][1024];
  __shared__ float wt_s[16][260];         // Wtag half for this dir, padded stride
  __shared__ float pfp_s[2][16][16];

  int tid = threadIdx.x;
  int len0 = seq_lens[b0], len1 = seq_lens[b1];

  for (int i = tid; i < 2048; i += 512)
    sent_s[i >> 10][i & 1023] = sentence[(size_t)(b0 + (i >> 10)) * 1024 + (i & 1023)];
  for (int i = tid; i < 4096; i += 512) {
    int k = i >> 8, j = i & 255;
    wt_s[k][j] = ws_c[OFF_WTAGD + (size_t)d * 4096 + i];
  }
  {  // h0 init: 512 threads cover [2][256]
    int bb = tid >> 8, u = tid & 255;
    h_s[bb][u] = h0p[((size_t)d * 64 + b0 + bb) * 256 + u];
  }
  float cc;  // cell state for (batch tid>>8, unit tid&255)
  {
    int bb = tid >> 8, u = tid & 255;
    cc = c0p[((size_t)d * 64 + b0 + bb) * 256 + u];
  }
  float2 bias_v = *(const float2*)(ws_c + OFF_BIAS + (size_t)d * 1024 + 2 * tid);
  __syncthreads();  // sent_s ready before prologue gather

  // prologue: gather x for first step into buffer 0
  int t0 = d ? 1023 : 0;
  if (tid < 128) {
    int bb = tid >> 6, l = tid & 63;
    int row = sent_s[bb][t0];
    *(float4*)&x_s[0][bb][l * 4] = *(const float4*)(emb + (size_t)row * 256 + l * 4);
  }
  __syncthreads();

  float* featsD = ws_mut + OFF_FEATS + (size_t)d * 1048576;
  int c2 = 2 * tid;

  for (int s = 0; s < 1024; ++s) {
    int t = d ? (1023 - s) : s;
    int cur = s & 1, nxt = cur ^ 1;
    // issue prefetch of next step's x rows (stashed in phase B)
    float4 pf = {0, 0, 0, 0};
    if (tid < 128) {
      int sn = (s < 1023) ? (s + 1) : 1023;
      int tn = d ? (1023 - sn) : sn;
      int bb = tid >> 6, l = tid & 63;
      int row = sent_s[bb][tn];
      pf = *(const float4*)(emb + (size_t)row * 256 + l * 4);
    }
    // ---- phase A: z[b][c2..c2+1] = bias + x@Wih^T + h@Whh^T ----
    float2 a0 = bias_v, a1 = bias_v;
#pragma unroll 4
    for (int k = 0; k < 256; k += 4) {
      float4 xv0 = *(const float4*)&x_s[cur][0][k];
      float4 xv1 = *(const float4*)&x_s[cur][1][k];
      float4 hv0 = *(const float4*)&h_s[0][k];
      float4 hv1 = *(const float4*)&h_s[1][k];
      const float* wi = Wih + (size_t)k * 1024 + c2;
      const float* wh = Whh + (size_t)k * 1024 + c2;
      float2 wi0 = *(const float2*)(wi);
      float2 wi1 = *(const float2*)(wi + 1024);
      float2 wi2 = *(const float2*)(wi + 2048);
      float2 wi3 = *(const float2*)(wi + 3072);
      float2 wh0 = *(const float2*)(wh);
      float2 wh1 = *(const float2*)(wh + 1024);
      float2 wh2 = *(const float2*)(wh + 2048);
      float2 wh3 = *(const float2*)(wh + 3072);
      a0.x = fmaf(wi0.x, xv0.x, a0.x); a0.y = fmaf(wi0.y, xv0.x, a0.y);
      a0.x = fmaf(wi1.x, xv0.y, a0.x); a0.y = fmaf(wi1.y, xv0.y, a0.y);
      a0.x = fmaf(wi2.x, xv0.z, a0.x); a0.y = fmaf(wi2.y, xv0.z, a0.y);
      a0.x = fmaf(wi3.x, xv0.w, a0.x); a0.y = fmaf(wi3.y, xv0.w, a0.y);
      a0.x = fmaf(wh0.x, hv0.x, a0.x); a0.y = fmaf(wh0.y, hv0.x, a0.y);
      a0.x = fmaf(wh1.x, hv0.y, a0.x); a0.y = fmaf(wh1.y, hv0.y, a0.y);
      a0.x = fmaf(wh2.x, hv0.z, a0.x); a0.y = fmaf(wh2.y, hv0.z, a0.y);
      a0.x = fmaf(wh3.x, hv0.w, a0.x); a0.y = fmaf(wh3.y, hv0.w, a0.y);
      a1.x = fmaf(wi0.x, xv1.x, a1.x); a1.y = fmaf(wi0.y, xv1.x, a1.y);
      a1.x = fmaf(wi1.x, xv1.y, a1.x); a1.y = fmaf(wi1.y, xv1.y, a1.y);
      a1.x = fmaf(wi2.x, xv1.z, a1.x); a1.y = fmaf(wi2.y, xv1.z, a1.y);
      a1.x = fmaf(wi3.x, xv1.w, a1.x); a1.y = fmaf(wi3.y, xv1.w, a1.y);
      a1.x = fmaf(wh0.x, hv1.x, a1.x); a1.y = fmaf(wh0.y, hv1.x, a1.y);
      a1.x = fmaf(wh1.x, hv1.y, a1.x); a1.y = fmaf(wh1.y, hv1.y, a1.y);
      a1.x = fmaf(wh2.x, hv1.z, a1.x); a1.y = fmaf(wh2.y, hv1.z, a1.y);
      a1.x = fmaf(wh3.x, hv1.w, a1.x); a1.y = fmaf(wh3.y, hv1.w, a1.y);
    }
    *(float2*)&z_s[0][c2] = a0;   // lane stride 2 dwords: 2-way bank alias = free
    *(float2*)&z_s[1][c2] = a1;
    __syncthreads();  // S1
    // ---- phase B: gates; each thread = (batch tid>>8, unit tid&255) ----
    {
      int bb = tid >> 8, u = tid & 255;
      float iv = z_s[bb][u], fv = z_s[bb][u + 256];
      float gv = z_s[bb][u + 512], ov = z_s[bb][u + 768];
      float cn = sigf(fv) * cc + sigf(iv) * tanhf(gv);
      float hn = sigf(ov) * tanhf(cn);
      bool m = t < ((bb == 0) ? len0 : len1);
      cc = m ? cn : cc;
      h_s[bb][u] = m ? hn : h_s[bb][u];
    }
    if (tid < 128) {
      int bb = tid >> 6, l = tid & 63;
      *(float4*)&x_s[nxt][bb][l * 4] = pf;
    }
    __syncthreads();  // S2
    // ---- phase C: partial tag-head, lanes walk consecutive LDS words ----
    {
      int bb = tid >> 8, r = tid & 255;
      int ks = r >> 4, jg = r & 15;
      float p = 0.0f;
#pragma unroll
      for (int i = 0; i < 16; ++i)
        p = fmaf(h_s[bb][jg + 16 * i], wt_s[ks][jg + 16 * i], p);
      pfp_s[bb][ks][jg] = p;
    }
    __syncthreads();  // S3
    // ---- phase D: reduce + store per-dir feats ----
    if (tid < 32) {
      int b = tid >> 4, k = tid & 15;
      float sum = 0.0f;
#pragma unroll
      for (int i = 0; i < 16; ++i) sum += pfp_s[b][k][i];
      featsD[(size_t)(b0 + b) * 16384 + (size_t)t * 16 + k] = sum;
    }
  }
}

// ---------------- Viterbi + backtrace, one wave per batch element ----------------
__global__ __launch_bounds__(64) void k_viterbi(const float* __restrict__ ws_c,
                                                const float* __restrict__ trans,
                                                const int* __restrict__ seq_lens,
                                                float* __restrict__ out) {
  __shared__ char bp_s[1024][12];
  int b = blockIdx.x, lane = threadIdx.x;
  int len = seq_lens[b];
  float trow[12];
#pragma unroll
  for (int p = 0; p < 12; ++p) trow[p] = (lane < 12) ? trans[lane * 12 + p] : 0.0f;
  float tb = (lane < 16) ? ws_c[OFF_BTAG + lane] : 0.0f;
  float fv = (lane == 10) ? 0.0f : NEG10K;  // START=10
  const float* ff = ws_c + OFF_FEATS + (size_t)b * 16384;
  const float* fb = ws_c + OFF_FEATS + 1048576 + (size_t)b * 16384;
  for (int t = 0; t < 1024; ++t) {
    float ft = (lane < 16) ? (ff[t * 16 + lane] + fb[t * 16 + lane] + tb) : 0.0f;
    float best = -3.0e38f; int arg = 0;
#pragma unroll
    for (int p = 0; p < 12; ++p) {
      float s = __shfl(fv, p) + trow[p];
      if (s > best) { best = s; arg = p; }  // strict >: first-max like jnp.argmax
    }
    bool m = t < len;
    if (m) fv = best + ft;
    if (lane < 12) bp_s[t][lane] = (char)(m ? arg : lane);
  }
  float term = (lane < 12) ? fv + trans[132 + lane] : -3.0e38f;  // STOP row = 11
  float bestv = -3.0e38f; int bestp = 0;
#pragma unroll
  for (int p = 0; p < 12; ++p) {
    float v = __shfl(term, p);
    if (v > bestv) { bestv = v; bestp = p; }
  }
  __syncthreads();
  if (lane == 0) {
    out[b] = bestv;
    int tag = bestp;
    float* po = out + 64 + (size_t)b * 1024;
    for (int t = 1023; t >= 0; --t) {
      po[t] = (t < len) ? (float)tag : 0.0f;
      tag = bp_s[t][tag];
    }
  }
}

extern "C" void kernel_launch(void* const* d_in, const int* in_sizes, int n_in,
                              void* d_out, int out_size, void* d_ws, size_t ws_size,
                              hipStream_t stream) {
  (void)in_sizes; (void)n_in; (void)out_size;
  const int*   sentence = (const int*)d_in[0];
  const int*   seq_lens = (const int*)d_in[1];
  const float* emb      = (const float*)d_in[2];
  const float* wih_f    = (const float*)d_in[3];
  const float* whh_f    = (const float*)d_in[4];
  const float* bih_f    = (const float*)d_in[5];
  const float* bhh_f    = (const float*)d_in[6];
  const float* wih_b    = (const float*)d_in[7];
  const float* whh_b    = (const float*)d_in[8];
  const float* bih_b    = (const float*)d_in[9];
  const float* bhh_b    = (const float*)d_in[10];
  const float* wtag     = (const float*)d_in[11];
  const float* btag     = (const float*)d_in[12];
  const float* trans    = (const float*)d_in[13];
  const float* h0p      = (const float*)d_in[14];
  const float* c0p      = (const float*)d_in[15];
  float* ws  = (float*)d_ws;
  float* out = (float*)d_out;
  if (ws_size < WS_FLOATS * sizeof(float)) return;  // ~12.6 MB scratch

  k_transpose<<<dim3(8, 32, 4), 256, 0, stream>>>(wih_f, wih_b, whh_f, whh_b, ws);
  k_prep_small<<<41, 256, 0, stream>>>(bih_f, bhh_f, bih_b, bhh_b, wtag, btag, ws);
  k_lstm<<<64, 512, 0, stream>>>(ws, sentence, emb, h0p, c0p, seq_lens, ws);
  k_viterbi<<<64, 64, 0, stream>>>(ws, trans, seq_lens, out);
}

// Round 4
// 10140.596 us; speedup vs baseline: 3.0120x; 3.0120x over previous
//
#include <hip/hip_runtime.h>
#include <math.h>

#define NEG10K -10000.0f
// K=12 tags, START=10, STOP=11, B=64, T=1024, V=50000, D=256, Hh=256, 4Hh=1024

// ---------------- workspace layout (float offsets) ----------------
static const size_t OFF_WT_IH = 0;                  // [2][256][1024]  Wih^T per dir
static const size_t OFF_WT_HH = 524288;             // [2][256][1024]  Whh^T per dir
static const size_t OFF_BIAS  = 1048576;            // [2][1024]       bih+bhh
static const size_t OFF_WTAGD = 1050624;            // [2][16][256]    Wtag halves, k-padded to 16
static const size_t OFF_BTAG  = 1058816;            // [16]
static const size_t OFF_FEATS = 1058832;            // [2][64][1024][16] per-dir partial feats
static const size_t OFF_HC    = 3155984;            // [2][64][256] h carry between chunks
static const size_t OFF_CC    = 3188752;            // [2][64][256] c carry
static const size_t OFF_G     = 3221520;            // [2][64][chunkT][1024] input projections
// fixed part = 12.9 MB; G adds 131072*chunkT floats

__device__ __forceinline__ float sigf(float x) { return 1.0f / (1.0f + expf(-x)); }

// ---------------- weight transposes: [1024][256] -> [256][1024] ----------------
__global__ __launch_bounds__(256) void k_transpose(
    const float* __restrict__ wih_f, const float* __restrict__ wih_b,
    const float* __restrict__ whh_f, const float* __restrict__ whh_b,
    float* __restrict__ ws) {
  __shared__ float tile[32][33];
  int z = blockIdx.z;
  const float* src = (z == 0) ? wih_f : (z == 1) ? wih_b : (z == 2) ? whh_f : whh_b;
  float* dst = ws + ((z < 2) ? (OFF_WT_IH + (size_t)z * 262144)
                             : (OFF_WT_HH + (size_t)(z - 2) * 262144));
  int r0 = blockIdx.y * 32;  // over 1024 rows of src
  int c0 = blockIdx.x * 32;  // over 256 cols of src
  int tid = threadIdx.x;
  int c = tid & 31, rg = tid >> 5;
#pragma unroll
  for (int i = 0; i < 4; ++i) {
    int r = rg * 4 + i;
    tile[r][c] = src[(size_t)(r0 + r) * 256 + c0 + c];
  }
  __syncthreads();
  int r2 = tid & 31, cg = tid >> 5;
#pragma unroll
  for (int i = 0; i < 4; ++i) {
    int ccv = cg * 4 + i;
    dst[(size_t)(c0 + ccv) * 1024 + r0 + r2] = tile[r2][ccv];
  }
}

// ---------------- small prep: bias combine, Wtag halves (pad K->16), btag pad ----------------
__global__ __launch_bounds__(256) void k_prep_small(
    const float* __restrict__ bih_f, const float* __restrict__ bhh_f,
    const float* __restrict__ bih_b, const float* __restrict__ bhh_b,
    const float* __restrict__ wtag, const float* __restrict__ btag,
    float* __restrict__ ws) {
  int i = blockIdx.x * 256 + threadIdx.x;
  if (i < 2048) {
    int d = i >> 10, n = i & 1023;
    ws[OFF_BIAS + i] = d ? (bih_b[n] + bhh_b[n]) : (bih_f[n] + bhh_f[n]);
  } else if (i < 2048 + 8192) {
    int r = i - 2048;
    int d = r >> 12, rem = r & 4095;
    int k = rem >> 8, j = rem & 255;
    ws[OFF_WTAGD + r] = (k < 12) ? wtag[(size_t)k * 512 + d * 256 + j] : 0.0f;
  } else if (i < 2048 + 8192 + 16) {
    int kk = i - 10240;
    ws[OFF_BTAG + kk] = (kk < 12) ? btag[kk] : 0.0f;
  }
}

// ---------------- G chunk = gather(emb, sentence) @ Wih^T + bias ----------------
// grid (16 n-tiles, chunkT m-tiles, 2 dirs), 256 thr, 64x64 tile, 4x4/thread.
// Row m of chunk -> (b = m>>cshift, tt = m&cmask); dir 1 rows are time-reversed
// so G[d][b][s] is the input for step s of that dir's chunk.
__global__ __launch_bounds__(256) void k_gemm_g(
    const int* __restrict__ sentence, const float* __restrict__ emb,
    const float* __restrict__ ws_c, float* __restrict__ G,
    int t0, int cshift) {
  __shared__ float As[32][64];
  __shared__ float Bs[32][64];
  __shared__ int idx_s[64];
  int d = blockIdx.z;
  int m0 = blockIdx.y * 64, n0 = blockIdx.x * 64;
  int tid = threadIdx.x;
  int cmask = (1 << cshift) - 1;
  const float* Wt = ws_c + OFF_WT_IH + (size_t)d * 262144;
  if (tid < 64) {
    int m = m0 + tid;
    int b = m >> cshift, tt = m & cmask;
    int t = d ? (1023 - t0 - tt) : (t0 + tt);
    idx_s[tid] = sentence[(size_t)b * 1024 + t];
  }
  __syncthreads();
  float acc[4][4] = {};
  int tm = tid >> 4, tn = tid & 15;
  int am = tid & 63, ak = (tid >> 6) * 8;
  int bn = (tid & 15) * 4, bk = tid >> 4;
  for (int k0 = 0; k0 < 256; k0 += 32) {
    const float* ar = emb + (size_t)idx_s[am] * 256 + k0 + ak;
    float4 a0 = *(const float4*)ar;
    float4 a1 = *(const float4*)(ar + 4);
    float4 b0 = *(const float4*)(Wt + (size_t)(k0 + bk) * 1024 + n0 + bn);
    float4 b1 = *(const float4*)(Wt + (size_t)(k0 + bk + 16) * 1024 + n0 + bn);
    As[ak + 0][am] = a0.x; As[ak + 1][am] = a0.y; As[ak + 2][am] = a0.z; As[ak + 3][am] = a0.w;
    As[ak + 4][am] = a1.x; As[ak + 5][am] = a1.y; As[ak + 6][am] = a1.z; As[ak + 7][am] = a1.w;
    *(float4*)&Bs[bk][bn] = b0;
    *(float4*)&Bs[bk + 16][bn] = b1;
    __syncthreads();
#pragma unroll
    for (int kk = 0; kk < 32; ++kk) {
      float4 av = *(const float4*)&As[kk][tm * 4];
      float4 bv = *(const float4*)&Bs[kk][tn * 4];
      float avf[4] = {av.x, av.y, av.z, av.w};
      float bvf[4] = {bv.x, bv.y, bv.z, bv.w};
#pragma unroll
      for (int i = 0; i < 4; ++i)
#pragma unroll
        for (int j = 0; j < 4; ++j) acc[i][j] = fmaf(avf[i], bvf[j], acc[i][j]);
    }
    __syncthreads();
  }
  float4 bias = *(const float4*)(ws_c + OFF_BIAS + (size_t)d * 1024 + n0 + tn * 4);
#pragma unroll
  for (int i = 0; i < 4; ++i) {
    int m = m0 + tm * 4 + i;
    int b = m >> cshift, tt = m & cmask;
    float* gp = G + (((size_t)d * 64 + b) * (size_t)(cmask + 1) + tt) * 1024 + n0 + tn * 4;
    float4 v;
    v.x = acc[i][0] + bias.x; v.y = acc[i][1] + bias.y;
    v.z = acc[i][2] + bias.z; v.w = acc[i][3] + bias.w;
    *(float4*)gp = v;
  }
}

// ---------------- recurrent LSTM (Whh only) + fused tag-head ----------------
// 64 WGs = (32 batch-pairs) x (2 dirs); 512 threads = 8 waves.
// Waves 0-3: k in [0,128); waves 4-7: k in [128,256). Thread owns 4 gate cols
// (float4 weight loads), computes both batches. z halves summed in phase B.
#define FMA4(A, W, S) { A.x = fmaf(W.x, S, A.x); A.y = fmaf(W.y, S, A.y); \
                        A.z = fmaf(W.z, S, A.z); A.w = fmaf(W.w, S, A.w); }
__global__ __launch_bounds__(512) void k_lstm_g(
    const float* __restrict__ ws_c, const float* __restrict__ G,
    const float* __restrict__ h0p, const float* __restrict__ c0p,
    const int* __restrict__ seq_lens, float* __restrict__ ws_mut,
    int t0, int chunkT, int first) {
  int d = blockIdx.x & 1;   // dir per XCD parity (both dirs' Whh = 2 MB fits L2 anyway)
  int pr = blockIdx.x >> 1;
  int b0 = pr * 2;
  const float* Whh = ws_c + OFF_WT_HH + (size_t)d * 262144;  // [256][1024]

  __shared__ float h_s[2][256];
  __shared__ float g_s[2][2][1024];   // [buf][batch][gatecol]
  __shared__ float z_s[2][2][1024];   // [khalf][batch][gatecol]
  __shared__ float wt_s[16][260];
  __shared__ float pfp_s[2][16][16];

  int tid = threadIdx.x;
  int bb = tid >> 8, u = tid & 255;   // bb doubles as k-half for phase A
  int c4 = u * 4;
  int len0 = seq_lens[b0], len1 = seq_lens[b0 + 1];
  int mylen = bb ? len1 : len0;

  for (int i = tid; i < 4096; i += 512)
    wt_s[i >> 8][i & 255] = ws_c[OFF_WTAGD + (size_t)d * 4096 + i];

  size_t hci = ((size_t)d * 64 + b0 + bb) * 256 + u;
  float cc;
  if (first) { h_s[bb][u] = h0p[hci]; cc = c0p[hci]; }
  else       { h_s[bb][u] = ws_c[OFF_HC + hci]; cc = ws_c[OFF_CC + hci]; }

  const float* Gb = G + (((size_t)d * 64 + b0 + bb) * (size_t)chunkT) * 1024;
  *(float4*)&g_s[0][bb][c4] = *(const float4*)(Gb + c4);  // step-0 inputs
  __syncthreads();

  float* featsD = ws_mut + OFF_FEATS + (size_t)d * 1048576;

  for (int s = 0; s < chunkT; ++s) {
    int sg = t0 + s;
    int t = d ? (1023 - sg) : sg;
    int cur = s & 1, nxt = cur ^ 1;
    // prefetch next step's G row (written to LDS in phase B -> full-step latency cover)
    int srow = (s + 1 < chunkT) ? (s + 1) : s;
    float4 gpf = *(const float4*)(Gb + (size_t)srow * 1024 + c4);
    // ---- phase A: half-k partial z for 4 cols x 2 batches ----
    float4 acc0 = {0, 0, 0, 0}, acc1 = {0, 0, 0, 0};
#pragma unroll 4
    for (int j = 0; j < 32; ++j) {
      int k = bb * 128 + j * 4;
      float4 hv0 = *(const float4*)&h_s[0][k];
      float4 hv1 = *(const float4*)&h_s[1][k];
      const float* wp = Whh + (size_t)k * 1024 + c4;
      float4 w0 = *(const float4*)(wp);
      float4 w1 = *(const float4*)(wp + 1024);
      float4 w2 = *(const float4*)(wp + 2048);
      float4 w3 = *(const float4*)(wp + 3072);
      FMA4(acc0, w0, hv0.x); FMA4(acc0, w1, hv0.y); FMA4(acc0, w2, hv0.z); FMA4(acc0, w3, hv0.w);
      FMA4(acc1, w0, hv1.x); FMA4(acc1, w1, hv1.y); FMA4(acc1, w2, hv1.z); FMA4(acc1, w3, hv1.w);
    }
    *(float4*)&z_s[bb][0][c4] = acc0;
    *(float4*)&z_s[bb][1][c4] = acc1;
    __syncthreads();  // S1
    // ---- phase B: gates for (batch bb, unit u); G already includes bias ----
    {
      float zi = z_s[0][bb][u]       + z_s[1][bb][u]       + g_s[cur][bb][u];
      float zf = z_s[0][bb][u + 256] + z_s[1][bb][u + 256] + g_s[cur][bb][u + 256];
      float zg = z_s[0][bb][u + 512] + z_s[1][bb][u + 512] + g_s[cur][bb][u + 512];
      float zo = z_s[0][bb][u + 768] + z_s[1][bb][u + 768] + g_s[cur][bb][u + 768];
      float cn = sigf(zf) * cc + sigf(zi) * tanhf(zg);
      float hn = sigf(zo) * tanhf(cn);
      bool m = t < mylen;
      cc = m ? cn : cc;
      h_s[bb][u] = m ? hn : h_s[bb][u];
    }
    *(float4*)&g_s[nxt][bb][c4] = gpf;
    __syncthreads();  // S2
    // ---- phase C: partial tag-head ----
    {
      int ks = u >> 4, jg = u & 15;
      float p = 0.0f;
#pragma unroll
      for (int i = 0; i < 16; ++i)
        p = fmaf(h_s[bb][jg + 16 * i], wt_s[ks][jg + 16 * i], p);
      pfp_s[bb][ks][jg] = p;
    }
    __syncthreads();  // S3
    if (tid < 32) {
      int b = tid >> 4, k = tid & 15;
      float sum = 0.0f;
#pragma unroll
      for (int i = 0; i < 16; ++i) sum += pfp_s[b][k][i];
      featsD[(size_t)(b0 + b) * 16384 + (size_t)t * 16 + k] = sum;
    }
  }
  ws_mut[OFF_HC + hci] = h_s[bb][u];
  ws_mut[OFF_CC + hci] = cc;
}

// ---------------- fallback fused LSTM (round-2, known-good) ----------------
__global__ __launch_bounds__(256) void k_lstm_fused(
    const float* __restrict__ ws_c, const int* __restrict__ sentence,
    const float* __restrict__ emb, const float* __restrict__ h0p,
    const float* __restrict__ c0p, const int* __restrict__ seq_lens,
    float* __restrict__ ws_mut) {
  int d = blockIdx.x & 1;
  int pr = blockIdx.x >> 1;
  int b0 = pr * 2, b1 = b0 + 1;
  const float* Wih = ws_c + OFF_WT_IH + (size_t)d * 262144;
  const float* Whh = ws_c + OFF_WT_HH + (size_t)d * 262144;
  __shared__ float h_s[2][256];
  __shared__ float x_s[2][2][256];
  __shared__ float z_s[2][1024];
  __shared__ int   sent_s[2][1024];
  __shared__ float wt_s[16][260];
  __shared__ float pfp_s[2][16][8];
  int tid = threadIdx.x;
  int len0 = seq_lens[b0], len1 = seq_lens[b1];
  for (int i = tid; i < 2048; i += 256)
    sent_s[i >> 10][i & 1023] = sentence[(size_t)(b0 + (i >> 10)) * 1024 + (i & 1023)];
  for (int i = tid; i < 4096; i += 256)
    wt_s[i >> 8][i & 255] = ws_c[OFF_WTAGD + (size_t)d * 4096 + i];
  h_s[0][tid] = h0p[((size_t)d * 64 + b0) * 256 + tid];
  h_s[1][tid] = h0p[((size_t)d * 64 + b1) * 256 + tid];
  float cc0 = c0p[((size_t)d * 64 + b0) * 256 + tid];
  float cc1 = c0p[((size_t)d * 64 + b1) * 256 + tid];
  int c4 = tid * 4;
  float4 bias_v = *(const float4*)(ws_c + OFF_BIAS + (size_t)d * 1024 + c4);
  __syncthreads();
  int t0 = d ? 1023 : 0;
  if (tid < 128) {
    int bb = tid >> 6, l = tid & 63;
    int row = sent_s[bb][t0];
    *(float4*)&x_s[0][bb][l * 4] = *(const float4*)(emb + (size_t)row * 256 + l * 4);
  }
  __syncthreads();
  float* featsD = ws_mut + OFF_FEATS + (size_t)d * 1048576;
  for (int s = 0; s < 1024; ++s) {
    int t = d ? (1023 - s) : s;
    int cur = s & 1, nxt = cur ^ 1;
    float4 pf = {0, 0, 0, 0};
    if (tid < 128) {
      int sn = (s < 1023) ? (s + 1) : 1023;
      int tn = d ? (1023 - sn) : sn;
      int bb = tid >> 6, l = tid & 63;
      pf = *(const float4*)(emb + (size_t)sent_s[bb][tn] * 256 + l * 4);
    }
    float4 a0 = bias_v, a1 = bias_v;
#pragma unroll 4
    for (int k = 0; k < 256; k += 4) {
      float4 xv0 = *(const float4*)&x_s[cur][0][k];
      float4 xv1 = *(const float4*)&x_s[cur][1][k];
      float4 hv0 = *(const float4*)&h_s[0][k];
      float4 hv1 = *(const float4*)&h_s[1][k];
      const float* wi = Wih + (size_t)k * 1024 + c4;
      const float* wh = Whh + (size_t)k * 1024 + c4;
      float4 wi0 = *(const float4*)(wi);
      float4 wi1 = *(const float4*)(wi + 1024);
      float4 wi2 = *(const float4*)(wi + 2048);
      float4 wi3 = *(const float4*)(wi + 3072);
      float4 wh0 = *(const float4*)(wh);
      float4 wh1 = *(const float4*)(wh + 1024);
      float4 wh2 = *(const float4*)(wh + 2048);
      float4 wh3 = *(const float4*)(wh + 3072);
      FMA4(a0, wi0, xv0.x); FMA4(a0, wi1, xv0.y); FMA4(a0, wi2, xv0.z); FMA4(a0, wi3, xv0.w);
      FMA4(a0, wh0, hv0.x); FMA4(a0, wh1, hv0.y); FMA4(a0, wh2, hv0.z); FMA4(a0, wh3, hv0.w);
      FMA4(a1, wi0, xv1.x); FMA4(a1, wi1, xv1.y); FMA4(a1, wi2, xv1.z); FMA4(a1, wi3, xv1.w);
      FMA4(a1, wh0, hv1.x); FMA4(a1, wh1, hv1.y); FMA4(a1, wh2, hv1.z); FMA4(a1, wh3, hv1.w);
    }
    *(float4*)&z_s[0][c4] = a0;
    *(float4*)&z_s[1][c4] = a1;
    __syncthreads();
    {
      float iv = z_s[0][tid], fv = z_s[0][tid + 256];
      float gv = z_s[0][tid + 512], ov = z_s[0][tid + 768];
      float cn = sigf(fv) * cc0 + sigf(iv) * tanhf(gv);
      float hn = sigf(ov) * tanhf(cn);
      bool m = t < len0;
      cc0 = m ? cn : cc0;
      h_s[0][tid] = m ? hn : h_s[0][tid];
    }
    {
      float iv = z_s[1][tid], fv = z_s[1][tid + 256];
      float gv = z_s[1][tid + 512], ov = z_s[1][tid + 768];
      float cn = sigf(fv) * cc1 + sigf(iv) * tanhf(gv);
      float hn = sigf(ov) * tanhf(cn);
      bool m = t < len1;
      cc1 = m ? cn : cc1;
      h_s[1][tid] = m ? hn : h_s[1][tid];
    }
    if (tid < 128) {
      int bb = tid >> 6, l = tid & 63;
      *(float4*)&x_s[nxt][bb][l * 4] = pf;
    }
    __syncthreads();
    {
      int b2 = tid >> 7, r = tid & 127;
      int ks = r >> 3, jg = r & 7;
      const float* hv = &h_s[b2][jg * 32];
      const float* wv = &wt_s[ks][jg * 32];
      float p = 0.0f;
#pragma unroll
      for (int i = 0; i < 32; ++i) p = fmaf(hv[i], wv[i], p);
      pfp_s[b2][ks][jg] = p;
    }
    __syncthreads();
    if (tid < 32) {
      int b = tid >> 4, k = tid & 15;
      float sum = 0.0f;
#pragma unroll
      for (int i = 0; i < 8; ++i) sum += pfp_s[b][k][i];
      featsD[(size_t)(b0 + b) * 16384 + (size_t)t * 16 + k] = sum;
    }
  }
}

// ---------------- Viterbi + backtrace, one wave per batch element ----------------
__global__ __launch_bounds__(64) void k_viterbi(const float* __restrict__ ws_c,
                                                const float* __restrict__ trans,
                                                const int* __restrict__ seq_lens,
                                                float* __restrict__ out) {
  __shared__ char bp_s[1024][12];
  int b = blockIdx.x, lane = threadIdx.x;
  int len = seq_lens[b];
  float trow[12];
#pragma unroll
  for (int p = 0; p < 12; ++p) trow[p] = (lane < 12) ? trans[lane * 12 + p] : 0.0f;
  float tb = (lane < 16) ? ws_c[OFF_BTAG + lane] : 0.0f;
  float fv = (lane == 10) ? 0.0f : NEG10K;  // START=10
  const float* ff = ws_c + OFF_FEATS + (size_t)b * 16384;
  const float* fb = ws_c + OFF_FEATS + 1048576 + (size_t)b * 16384;
  for (int t = 0; t < 1024; ++t) {
    float ft = (lane < 16) ? (ff[t * 16 + lane] + fb[t * 16 + lane] + tb) : 0.0f;
    float best = -3.0e38f; int arg = 0;
#pragma unroll
    for (int p = 0; p < 12; ++p) {
      float s = __shfl(fv, p) + trow[p];
      if (s > best) { best = s; arg = p; }
    }
    bool m = t < len;
    if (m) fv = best + ft;
    if (lane < 12) bp_s[t][lane] = (char)(m ? arg : lane);
  }
  float term = (lane < 12) ? fv + trans[132 + lane] : -3.0e38f;  // STOP row = 11
  float bestv = -3.0e38f; int bestp = 0;
#pragma unroll
  for (int p = 0; p < 12; ++p) {
    float v = __shfl(term, p);
    if (v > bestv) { bestv = v; bestp = p; }
  }
  __syncthreads();
  if (lane == 0) {
    out[b] = bestv;
    int tag = bestp;
    float* po = out + 64 + (size_t)b * 1024;
    for (int t = 1023; t >= 0; --t) {
      po[t] = (t < len) ? (float)tag : 0.0f;
      tag = bp_s[t][tag];
    }
  }
}

extern "C" void kernel_launch(void* const* d_in, const int* in_sizes, int n_in,
                              void* d_out, int out_size, void* d_ws, size_t ws_size,
                              hipStream_t stream) {
  (void)in_sizes; (void)n_in; (void)out_size;
  const int*   sentence = (const int*)d_in[0];
  const int*   seq_lens = (const int*)d_in[1];
  const float* emb      = (const float*)d_in[2];
  const float* wih_f    = (const float*)d_in[3];
  const float* whh_f    = (const float*)d_in[4];
  const float* bih_f    = (const float*)d_in[5];
  const float* bhh_f    = (const float*)d_in[6];
  const float* wih_b    = (const float*)d_in[7];
  const float* whh_b    = (const float*)d_in[8];
  const float* bih_b    = (const float*)d_in[9];
  const float* bhh_b    = (const float*)d_in[10];
  const float* wtag     = (const float*)d_in[11];
  const float* btag     = (const float*)d_in[12];
  const float* trans    = (const float*)d_in[13];
  const float* h0p      = (const float*)d_in[14];
  const float* c0p      = (const float*)d_in[15];
  float* ws  = (float*)d_ws;
  float* out = (float*)d_out;
  size_t avail = ws_size / 4;
  if (avail < OFF_FEATS + 2097152) return;  // below even the fused path's 12.6 MB

  // pick largest time-chunk whose G buffer fits the workspace
  int chunkT = 0;
  const int opts[5] = {512, 256, 128, 64, 32};
  for (int i = 0; i < 5; ++i)
    if (OFF_G + (size_t)131072 * opts[i] <= avail) { chunkT = opts[i]; break; }

  k_transpose<<<dim3(8, 32, 4), 256, 0, stream>>>(wih_f, wih_b, whh_f, whh_b, ws);
  k_prep_small<<<41, 256, 0, stream>>>(bih_f, bhh_f, bih_b, bhh_b, wtag, btag, ws);
  if (chunkT) {
    int cshift = 31 - __builtin_clz(chunkT);
    int nc = 1024 / chunkT;
    for (int c = 0; c < nc; ++c) {
      int t0 = c * chunkT;
      k_gemm_g<<<dim3(16, chunkT, 2), 256, 0, stream>>>(sentence, emb, ws, ws + OFF_G,
                                                        t0, cshift);
      k_lstm_g<<<64, 512, 0, stream>>>(ws, ws + OFF_G, h0p, c0p, seq_lens, ws,
                                       t0, chunkT, c == 0);
    }
  } else {
    k_lstm_fused<<<64, 256, 0, stream>>>(ws, sentence, emb, h0p, c0p, seq_lens, ws);
  }
  k_viterbi<<<64, 64, 0, stream>>>(ws, trans, seq_lens, out);
}